// Round 2
// baseline (6047.539 us; speedup 1.0000x reference)
//
#include <hip/hip_runtime.h>
#include <stdint.h>

#define T_STEPS 512
#define NB 64
#define NI 512
#define NH 1024
#define NBLK 128
// gate-cols total = 4*NH = 4096

typedef __attribute__((ext_vector_type(8))) short short8;
typedef __attribute__((ext_vector_type(4))) float floatx4;
typedef __attribute__((ext_vector_type(16))) float floatx16;
typedef __attribute__((ext_vector_type(4))) unsigned short ushortx4;

__device__ __forceinline__ unsigned short f2bf(float f) {
  union { float f; uint32_t u; } v; v.f = f;
  return (unsigned short)((v.u + 0x7FFFu + ((v.u >> 16) & 1u)) >> 16);
}
__device__ __forceinline__ float bf2f(unsigned short s) {
  union { uint32_t u; float f; } v; v.u = ((uint32_t)s) << 16; return v.f;
}
__device__ __forceinline__ float sigmoid_f(float x) {
  return 1.0f / (1.0f + __expf(-x));
}
__device__ __forceinline__ float tanh_f(float x) {
  float xx = fminf(fmaxf(x, -15.0f), 15.0f);
  float e = __expf(2.0f * xx);
  return (e - 1.0f) / (e + 1.0f);
}

// ---------------- prep kernels ----------------

// X fp32 [T*B*I] -> bf16, 4 elems/thread, exact grid
__global__ void convert_x(const float* __restrict__ X, unsigned short* __restrict__ Xb) {
  int i = blockIdx.x * 256 + threadIdx.x;
  floatx4 x = ((const floatx4*)X)[i];
  ushortx4 o;
  o[0] = f2bf(x[0]); o[1] = f2bf(x[1]); o[2] = f2bf(x[2]); o[3] = f2bf(x[3]);
  ((ushortx4*)Xb)[i] = o;
}

// in [G][K][N] fp32 -> out [G][N][K] bf16 (n-major so K is contiguous)
__global__ void transpose_bf16(const float* __restrict__ in, unsigned short* __restrict__ outp,
                               int K, int N) {
  __shared__ float tile[64][65];
  int g = blockIdx.z;
  int k0 = blockIdx.x * 64, n0 = blockIdx.y * 64;
  int tx = threadIdx.x & 63, ty = threadIdx.x >> 6;
  const float* src = in + (size_t)g * K * N;
  unsigned short* dst = outp + (size_t)g * K * N;
#pragma unroll
  for (int i = 0; i < 16; i++) {
    int r = ty * 16 + i;
    tile[r][tx] = src[(size_t)(k0 + r) * N + n0 + tx];
  }
  __syncthreads();
#pragma unroll
  for (int i = 0; i < 16; i++) {
    int r = ty * 16 + i;
    dst[(size_t)(n0 + r) * K + k0 + tx] = f2bf(tile[tx][r]);
  }
}

// bias = bi + bh (fp32), hbuf0 = bf16(h0), zero barrier flags (packed, 128 dwords)
__global__ void prep_small(const float* __restrict__ bi, const float* __restrict__ bh,
                           const float* __restrict__ h0, float* __restrict__ bias,
                           unsigned short* __restrict__ hbuf0, unsigned* __restrict__ flags) {
  int i = blockIdx.x * 256 + threadIdx.x;
  if (i < NBLK) flags[i] = 0u;   // packed flags for dwordx2 polling
  if (i < 4 * NH) bias[i] = bi[i] + bh[i];
  if (i < NB * NH) hbuf0[i] = f2bf(h0[i]);
}

// ---------------- Zx GEMM -> block-major Zq layout ----------------
// Zq element index: ((((t*4 + g)*128 + bk)*2 + wm)*2 + half)*8 + jj)*16 + rr
// where b = wm*32 + row32, row32 = (rr&3) | (half<<2) | ((rr>>2)<<3), j = bk*8 + jj.
// This makes each persist-thread's per-step Zx slice one contiguous 32B chunk.
__global__ __launch_bounds__(256) void gemm_zx(
    const unsigned short* __restrict__ Xb,
    const unsigned short* __restrict__ WibT,
    const float* __restrict__ bias,
    unsigned short* __restrict__ Zq) {
  __shared__ __align__(16) unsigned short As[128][40];  // +8 pad
  __shared__ __align__(16) unsigned short Bs[128][40];
  __shared__ __align__(16) unsigned short stg[16384];   // 32 KB stage (2 t x 16 bk x 512)
  const int g = blockIdx.z;
  const int m0 = blockIdx.x * 128;
  const int n0 = blockIdx.y * 128;
  const int tid = threadIdx.x;
  const int lane = tid & 63;
  const int wave = tid >> 6;
  const int wm = wave & 1, wn = wave >> 1;
  const int fr = lane & 15;            // frag row (m for A, n for B)
  const int fq = (lane >> 4) * 8;      // frag k offset

  const unsigned short* Bsrc = WibT + (size_t)g * NH * NI;

  floatx4 acc[4][4];
#pragma unroll
  for (int a = 0; a < 4; a++)
#pragma unroll
    for (int b = 0; b < 4; b++)
#pragma unroll
      for (int z = 0; z < 4; z++) acc[a][b][z] = 0.0f;

  for (int k0 = 0; k0 < NI; k0 += 32) {
#pragma unroll
    for (int it = 0; it < 2; it++) {
      int c = tid + it * 256;            // 0..511
      int row = c >> 2, kc = (c & 3) * 8;
      *(uint4*)(&As[row][kc]) = *(const uint4*)(Xb + (size_t)(m0 + row) * NI + k0 + kc);
      *(uint4*)(&Bs[row][kc]) = *(const uint4*)(Bsrc + (size_t)(n0 + row) * NI + k0 + kc);
    }
    __syncthreads();
    short8 af[4], bf[4];
#pragma unroll
    for (int ms = 0; ms < 4; ms++) af[ms] = *(const short8*)(&As[wm * 64 + ms * 16 + fr][fq]);
#pragma unroll
    for (int ns = 0; ns < 4; ns++) bf[ns] = *(const short8*)(&Bs[wn * 64 + ns * 16 + fr][fq]);
#pragma unroll
    for (int ms = 0; ms < 4; ms++)
#pragma unroll
      for (int ns = 0; ns < 4; ns++)
        acc[ms][ns] = __builtin_amdgcn_mfma_f32_16x16x32_bf16(af[ms], bf[ns], acc[ms][ns], 0, 0, 0);
    __syncthreads();
  }

  // Epilogue: bias add + bf16 + scatter into LDS stage in Zq order, then
  // coalesced copy out (two contiguous 16 KB spans, one per t' in this tile).
#pragma unroll
  for (int ns = 0; ns < 4; ns++) {
    int jrel = wn * 64 + ns * 16 + fr;        // col - n0, 0..127
    float bs = bias[g * NH + n0 + jrel];
    int bkp = jrel >> 3, jj = jrel & 7;
#pragma unroll
    for (int ms = 0; ms < 4; ms++) {
#pragma unroll
      for (int r = 0; r < 4; r++) {
        int mrel = wm * 64 + ms * 16 + (lane >> 4) * 4 + r;   // 0..127
        int tp = mrel >> 6, b = mrel & 63;
        int wm2 = b >> 5, row32 = b & 31;
        int half2 = (row32 >> 2) & 1;
        int rr = (row32 & 3) | ((row32 >> 3) << 2);
        int idx = (((((tp * 16 + bkp) * 2 + wm2) * 2 + half2) * 8 + jj) * 16) + rr;
        stg[idx] = f2bf(acc[ms][ns][r] + bs);
      }
    }
  }
  __syncthreads();
  const size_t t0 = (size_t)(m0 >> 6);
  const int bk0 = n0 >> 3;
#pragma unroll
  for (int tp = 0; tp < 2; tp++) {
    size_t gbase = (((t0 + tp) * 4 + g) * 128 + bk0) * 512;   // elements
#pragma unroll
    for (int c = 0; c < 4; c++) {
      int e = c * 2048 + tid * 8;
      *(uint4*)(Zq + gbase + e) = *(const uint4*)(stg + tp * 8192 + e);
    }
  }
}

// ---------------- persistent recurrent kernel ----------------
// R5 changes vs R4 (10.4 us/step):
//  * Zx -> Zq block-major relayout: per-step per-thread Zx slice is one contiguous
//    32B chunk -> 2 coalesced global_load_dwordx4 nt (was 16 scalar bf16 loads at
//    8KB stride = 5x HBM overfetch + ~1-2us of scattered-HBM drain at step top).
//  * nt on Zq loads + out stores: Zx/out no longer thrash LLC, so dirty hbuf lines
//    stay LLC-resident -> bypass A-loads keep LLC-class latency.
//  * Zq prefetch issued right after the MFMA window (hidden under epilogue VALU);
//    out stores moved AFTER the flag post (off the release path).
//  * 2x unrolled t-loop with alternating named Zq register sets (no hoistable
//    register copy; prefetch regs consumed only after next step's post-Chunks
//    sched_barrier(0), by which point vmcnt hit 0 inside Chunks).
//  Sync protocol identical to R4 (verified): WT h stores + vmcnt(0) + packed flags
//  + bypass loads; WAW-safe via the full barrier + double buffer.

template<int G>
__device__ __forceinline__ void load_a(const unsigned short* ap, short8 (&areg)[64]) {
  asm volatile("global_load_dwordx4 %0, %1, off offset:%2 sc0 sc1"
               : "=v"(areg[G]) : "v"(ap), "i"(G * 32));
}

template<int G>
__device__ __forceinline__ void load_b(const unsigned short* bfr, int lane, short8 (&bs)[64]) {
  bs[G] = *(const short8*)(&bfr[((size_t)(G * 64) + lane) * 8]);
}

template<int G>
struct Prolog {
  static __device__ __forceinline__ void run(const unsigned short* ap, short8 (&areg)[64]) {
    load_a<G>(ap, areg);
    Prolog<G + 1>::run(ap, areg);
  }
};
template<>
struct Prolog<16> {
  static __device__ __forceinline__ void run(const unsigned short*, short8 (&)[64]) {}
};

template<int G>
struct Chunks {
  static __device__ __forceinline__ void run(const unsigned short* ap, const unsigned short* bfr,
                                             int lane, short8 (&areg)[64], short8 (&bs)[64],
                                             floatx16& acc0, floatx16& acc1) {
    if constexpr (G + 16 < 64) load_a<G + 16>(ap, areg);      // keep 16 in flight
    if constexpr (G + 4 < 64) load_b<G + 4>(bfr, lane, bs);   // B frag 4 ahead (ds)
    constexpr int NOUT = (G + 16 < 64) ? 16 : (63 - G);
    // wait chunk G; "+v" tie makes the MFMA data-dependent on this asm (rule #18),
    // "memory" pins later vmem below the counted region.
    asm volatile("s_waitcnt vmcnt(%1)" : "+v"(areg[G]) : "i"(NOUT) : "memory");
    if constexpr ((G & 1) == 0)
      acc0 = __builtin_amdgcn_mfma_f32_32x32x16_bf16(areg[G], bs[G], acc0, 0, 0, 0);
    else
      acc1 = __builtin_amdgcn_mfma_f32_32x32x16_bf16(areg[G], bs[G], acc1, 0, 0, 0);
    Chunks<G + 1>::run(ap, bfr, lane, areg, bs, acc0, acc1);
  }
};
template<>
struct Chunks<64> {
  static __device__ __forceinline__ void run(const unsigned short*, const unsigned short*,
                                             int, short8 (&)[64], short8 (&)[64],
                                             floatx16&, floatx16&) {}
};

__device__ __forceinline__ void lstm_step(
    int t, const unsigned short* __restrict__ Zq, unsigned short* __restrict__ hbuf,
    unsigned* __restrict__ flags, float* __restrict__ out,
    const unsigned short* bfr, const unsigned long long* fpq,
    int tid, int lane, int wm, int nl, int g0, int jj, int half, int bk, int j0,
    size_t zoff, const int (&brow)[16], float (&creg)[16],
    uint4 (&zc)[2], uint4 (&zn)[2]) {
  const int hsz = NB * NH;

  // ---- arrive: all 128 flags >= t (packed; dwordx2 per lane, agent-scope) ----
  if (t) {
    unsigned tgt = (unsigned)t;
    for (;;) {
      unsigned long long fv = __hip_atomic_load(fpq, __ATOMIC_RELAXED,
                                                __HIP_MEMORY_SCOPE_AGENT);
      unsigned a = (unsigned)fv, b2 = (unsigned)(fv >> 32);
      if (__all((int)((a >= tgt) && (b2 >= tgt)))) break;
      __builtin_amdgcn_s_sleep(1);
    }
  }
  // clean vmcnt domain before the counted A-load window (drains prior out stores)
  asm volatile("s_waitcnt vmcnt(0)" ::: "memory");
  __builtin_amdgcn_sched_barrier(0);

  const unsigned short* hin = hbuf + (size_t)(t & 1) * hsz;
  unsigned short* hout = hbuf + (size_t)((t + 1) & 1) * hsz;
  const unsigned short* ap = hin + (size_t)(wm * 32 + nl) * NH + half * 8;

  floatx16 acc0, acc1;
#pragma unroll
  for (int z = 0; z < 16; z++) { acc0[z] = 0.0f; acc1[z] = 0.0f; }

  short8 areg[64];
  short8 bs[64];
  Prolog<0>::run(ap, areg);          // issue A chunks 0..15 (bypass loads)
  load_b<0>(bfr, lane, bs);
  load_b<1>(bfr, lane, bs);
  load_b<2>(bfr, lane, bs);
  load_b<3>(bfr, lane, bs);
  Chunks<0>::run(ap, bfr, lane, areg, bs, acc0, acc1);
  __builtin_amdgcn_sched_barrier(0);

  // Zq prefetch for t+1: one contiguous 32B nt load per thread, hidden under epilogue.
  if (t + 1 < T_STEPS) {
    const unsigned short* zp = Zq + (size_t)(t + 1) * 262144 + zoff;
    asm volatile("global_load_dwordx4 %0, %1, off nt" : "=v"(zn[0]) : "v"(zp));
    asm volatile("global_load_dwordx4 %0, %1, off offset:16 nt" : "=v"(zn[1]) : "v"(zp));
  }

#pragma unroll
  for (int z = 0; z < 16; z++) acc0[z] += acc1[z];

  // unpack this step's Zq chunk (regs valid: drained at previous release vmcnt(0))
  unsigned zd[8];
  zd[0] = zc[0].x; zd[1] = zc[0].y; zd[2] = zc[0].z; zd[3] = zc[0].w;
  zd[4] = zc[1].x; zd[5] = zc[1].y; zd[6] = zc[1].z; zd[7] = zc[1].w;

  float harr[16];
  // epilogue: gather all 4 gates across the quad {l, l^8, l^16, l^24}
#pragma unroll
  for (int r = 0; r < 16; r++) {
    unsigned dw = zd[r >> 1];
    float zxv = bf2f((unsigned short)((r & 1) ? (dw >> 16) : (dw & 0xffffu)));
    float z0 = acc0[r] + zxv;            // gate g0
    float z1 = __shfl_xor(z0, 8);        // gate g0^1
    float z2 = __shfl_xor(z0, 16);       // gate g0^2
    float z3 = __shfl_xor(z1, 16);       // gate g0^3
    bool bb0 = (g0 & 1) != 0, bb1 = (g0 & 2) != 0;
    float zf = bb1 ? (bb0 ? z3 : z2) : (bb0 ? z1 : z0);  // zq[g0]
    float zi = bb1 ? (bb0 ? z2 : z3) : (bb0 ? z0 : z1);  // zq[1^g0]
    float zg = bb1 ? (bb0 ? z1 : z0) : (bb0 ? z3 : z2);  // zq[2^g0]
    float zo = bb1 ? (bb0 ? z0 : z1) : (bb0 ? z2 : z3);  // zq[3^g0]
    float fg = sigmoid_f(zf);
    float ig = sigmoid_f(zi);
    float gg = tanh_f(zg);
    float og = sigmoid_f(zo);
    float c = fg * creg[r] + ig * gg;
    creg[r] = c;
    float h = og * tanh_f(c);
    harr[r] = h;
    if (g0 == 0) {  // one writer per (b, j) quad; agent-scope WT -> LLC
      __hip_atomic_store(&hout[(size_t)brow[r] * NH + j0 + jj], f2bf(h),
                         __ATOMIC_RELAXED, __HIP_MEMORY_SCOPE_AGENT);
    }
  }

  if (t + 1 < T_STEPS) {
    // ---- release: h stores (+ Zq prefetch) at coherence point, then post flag ----
    asm volatile("s_waitcnt vmcnt(0)" ::: "memory");
    __syncthreads();                                   // both waves drained
    if (tid == 0)
      __hip_atomic_store(flags + bk, (unsigned)(t + 1),
                         __ATOMIC_RELAXED, __HIP_MEMORY_SCOPE_AGENT);
  }

  // out stores off the release path (nt: bypass caches, drain during next spin)
  if (g0 == 0) {
#pragma unroll
    for (int r = 0; r < 16; r++) {
      size_t oidx = (size_t)brow[r] * NH + j0 + jj;
      __builtin_nontemporal_store(harr[r], &out[(size_t)t * hsz + oidx]);
      if (t == T_STEPS - 1)
        __builtin_nontemporal_store(harr[r], &out[(size_t)T_STEPS * hsz + oidx]);  // h_n
    }
  }
}

__global__ __launch_bounds__(128, 1) void lstm_persist(
    const unsigned short* __restrict__ Zq,
    const unsigned short* __restrict__ WhT,   // [4][NH(n)][NH(k)] bf16
    const float* __restrict__ c0,
    unsigned short* __restrict__ hbuf,        // 2 x NB x NH bf16
    unsigned* __restrict__ flags,             // NBLK packed dwords
    float* __restrict__ out) {
  __shared__ __align__(16) unsigned short bfr[64 * 64 * 8];  // [kk][lane][8] = 64 KB

  const int bk = blockIdx.x;
  const int j0 = bk * 8;
  const int tid = threadIdx.x;
  const int lane = tid & 63;
  const int wm = tid >> 6;        // wave = batch half (m-tile of 32)
  const int nl = lane & 31;       // MFMA col n (0..31): gate g0 = n>>3, h-col jj = n&7
  const int g0 = nl >> 3;
  const int jj = nl & 7;
  const int half = lane >> 5;

  // Fill B fragments: B[k][n] = Wh[g][k][j0+jj] = WhT[g][j0+jj][k]
  for (int i = 0; i < 32; i++) {
    int f = tid + i * 128;        // 0..4095 = kk*64 + lane
    int fl = f & 63, kk = f >> 6;
    int n = fl & 31;
    size_t wrow = (size_t)((n >> 3) * NH + j0 + (n & 7));
    int kb = kk * 16 + (fl >> 5) * 8;
    uint4 v = *(const uint4*)(WhT + wrow * NH + kb);
    *(uint4*)(&bfr[(size_t)f * 8]) = v;
  }

  // c state in C/D layout: row = (r&3) + 8*(r>>2) + 4*half  (rows within 32-tile)
  float creg[16];
  int brow[16];
#pragma unroll
  for (int r = 0; r < 16; r++) {
    brow[r] = wm * 32 + (r & 3) + 8 * (r >> 2) + 4 * half;
    creg[r] = c0[(size_t)brow[r] * NH + j0 + jj];
  }
  __syncthreads();

  const unsigned long long* fpq = (const unsigned long long*)flags + lane;
  const size_t zoff = (((((size_t)g0 * 128 + bk) * 2 + wm) * 2 + half) * 8 + jj) * 16;

  uint4 zA[2], zB[2];
  {  // t=0 prefetch (valid after the t=0 step-top vmcnt(0))
    const unsigned short* zp = Zq + zoff;
    asm volatile("global_load_dwordx4 %0, %1, off nt" : "=v"(zA[0]) : "v"(zp));
    asm volatile("global_load_dwordx4 %0, %1, off offset:16 nt" : "=v"(zA[1]) : "v"(zp));
  }

  for (int t2 = 0; t2 < T_STEPS; t2 += 2) {
    lstm_step(t2,     Zq, hbuf, flags, out, bfr, fpq, tid, lane, wm, nl, g0, jj, half,
              bk, j0, zoff, brow, creg, zA, zB);
    lstm_step(t2 + 1, Zq, hbuf, flags, out, bfr, fpq, tid, lane, wm, nl, g0, jj, half,
              bk, j0, zoff, brow, creg, zB, zA);
  }

  // c_n
  if (g0 == 0) {
#pragma unroll
    for (int r = 0; r < 16; r++)
      __builtin_nontemporal_store(
          creg[r], &out[(size_t)T_STEPS * NB * NH + NB * NH + (size_t)brow[r] * NH + j0 + jj]);
  }
}

// ---------------- host launcher ----------------
extern "C" void kernel_launch(void* const* d_in, const int* in_sizes, int n_in,
                              void* d_out, int out_size, void* d_ws, size_t ws_size,
                              hipStream_t stream) {
  const float* X  = (const float*)d_in[0];
  const float* h0 = (const float*)d_in[1];
  const float* c0 = (const float*)d_in[2];
  const float* Wi = (const float*)d_in[3];
  const float* Wh = (const float*)d_in[4];
  const float* bi = (const float*)d_in[5];
  const float* bh = (const float*)d_in[6];
  float* out = (float*)d_out;

  uint8_t* ws = (uint8_t*)d_ws;
  size_t off = 0;
  auto alloc = [&](size_t bytes) -> void* {
    void* p = ws + off;
    off += (bytes + 255) & ~(size_t)255;
    return p;
  };
  unsigned short* Zq   = (unsigned short*)alloc((size_t)T_STEPS * NB * 4096 * 2);  // 268 MB
  unsigned short* Xb   = (unsigned short*)alloc((size_t)T_STEPS * NB * NI * 2);    // 33.6 MB
  unsigned short* WibT = (unsigned short*)alloc((size_t)4 * NH * NI * 2);          // 4.2 MB
  unsigned short* WhT  = (unsigned short*)alloc((size_t)4 * NH * NH * 2);          // 8.4 MB
  float* bias          = (float*)alloc((size_t)4 * NH * 4);
  unsigned short* hbuf = (unsigned short*)alloc((size_t)2 * NB * NH * 2);
  unsigned* flags      = (unsigned*)alloc((size_t)NBLK * 32 * 4);                  // 16 KB (packed: first 512 B used)

  if (off > ws_size) {
    hipMemsetAsync(d_out, 0x7F, (size_t)out_size * 4, stream);
    return;
  }

  convert_x<<<16384, 256, 0, stream>>>(X, Xb);
  transpose_bf16<<<dim3(8, 16, 4), 256, 0, stream>>>(Wi, WibT, NI, NH);
  transpose_bf16<<<dim3(16, 16, 4), 256, 0, stream>>>(Wh, WhT, NH, NH);
  prep_small<<<256, 256, 0, stream>>>(bi, bh, h0, bias, hbuf, flags);
  gemm_zx<<<dim3(256, 8, 4), 256, 0, stream>>>(Xb, WibT, bias, Zq);

  lstm_persist<<<dim3(NBLK), dim3(128), 0, stream>>>(Zq, WhT, c0, hbuf, flags, out);
}

// Round 3
// 5880.575 us; speedup vs baseline: 1.0284x; 1.0284x over previous
//
#include <hip/hip_runtime.h>
#include <stdint.h>

#define T_STEPS 512
#define NB 64
#define NI 512
#define NH 1024
#define NBLK 128
#define DEPTH 32
// gate-cols total = 4*NH = 4096

typedef __attribute__((ext_vector_type(8))) short short8;
typedef __attribute__((ext_vector_type(4))) float floatx4;
typedef __attribute__((ext_vector_type(16))) float floatx16;
typedef __attribute__((ext_vector_type(4))) unsigned short ushortx4;

__device__ __forceinline__ unsigned short f2bf(float f) {
  union { float f; uint32_t u; } v; v.f = f;
  return (unsigned short)((v.u + 0x7FFFu + ((v.u >> 16) & 1u)) >> 16);
}
__device__ __forceinline__ float bf2f(unsigned short s) {
  union { uint32_t u; float f; } v; v.u = ((uint32_t)s) << 16; return v.f;
}
__device__ __forceinline__ float sigmoid_f(float x) {
  return 1.0f / (1.0f + __expf(-x));
}
__device__ __forceinline__ float tanh_f(float x) {
  float xx = fminf(fmaxf(x, -15.0f), 15.0f);
  float e = __expf(2.0f * xx);
  return (e - 1.0f) / (e + 1.0f);
}

// ---------------- prep kernels ----------------

// X fp32 [T*B*I] -> bf16, 4 elems/thread, exact grid
__global__ void convert_x(const float* __restrict__ X, unsigned short* __restrict__ Xb) {
  int i = blockIdx.x * 256 + threadIdx.x;
  floatx4 x = ((const floatx4*)X)[i];
  ushortx4 o;
  o[0] = f2bf(x[0]); o[1] = f2bf(x[1]); o[2] = f2bf(x[2]); o[3] = f2bf(x[3]);
  ((ushortx4*)Xb)[i] = o;
}

// in [G][K][N] fp32 -> out [G][N][K] bf16 (n-major so K is contiguous)
__global__ void transpose_bf16(const float* __restrict__ in, unsigned short* __restrict__ outp,
                               int K, int N) {
  __shared__ float tile[64][65];
  int g = blockIdx.z;
  int k0 = blockIdx.x * 64, n0 = blockIdx.y * 64;
  int tx = threadIdx.x & 63, ty = threadIdx.x >> 6;
  const float* src = in + (size_t)g * K * N;
  unsigned short* dst = outp + (size_t)g * K * N;
#pragma unroll
  for (int i = 0; i < 16; i++) {
    int r = ty * 16 + i;
    tile[r][tx] = src[(size_t)(k0 + r) * N + n0 + tx];
  }
  __syncthreads();
#pragma unroll
  for (int i = 0; i < 16; i++) {
    int r = ty * 16 + i;
    dst[(size_t)(n0 + r) * K + k0 + tx] = f2bf(tile[tx][r]);
  }
}

// bias = bi + bh (fp32), hbuf0 = bf16(h0), zero barrier flags (packed, 128 dwords)
__global__ void prep_small(const float* __restrict__ bi, const float* __restrict__ bh,
                           const float* __restrict__ h0, float* __restrict__ bias,
                           unsigned short* __restrict__ hbuf0, unsigned* __restrict__ flags) {
  int i = blockIdx.x * 256 + threadIdx.x;
  if (i < NBLK) flags[i] = 0u;   // packed flags for dwordx2 polling
  if (i < 4 * NH) bias[i] = bi[i] + bh[i];
  if (i < NB * NH) hbuf0[i] = f2bf(h0[i]);
}

// ---------------- Zx GEMM -> block-major Zq layout ----------------
// Zq element index: ((((t*4 + g)*128 + bk)*2 + wm)*2 + half)*8 + jj)*16 + rr
// where b = wm*32 + row32, row32 = (rr&3) | (half<<2) | ((rr>>2)<<3), j = bk*8 + jj.
// This makes each persist-thread's per-step Zx slice one contiguous 32B chunk.
__global__ __launch_bounds__(256) void gemm_zx(
    const unsigned short* __restrict__ Xb,
    const unsigned short* __restrict__ WibT,
    const float* __restrict__ bias,
    unsigned short* __restrict__ Zq) {
  __shared__ __align__(16) unsigned short As[128][40];  // +8 pad
  __shared__ __align__(16) unsigned short Bs[128][40];
  __shared__ __align__(16) unsigned short stg[16384];   // 32 KB stage (2 t x 16 bk x 512)
  const int g = blockIdx.z;
  const int m0 = blockIdx.x * 128;
  const int n0 = blockIdx.y * 128;
  const int tid = threadIdx.x;
  const int lane = tid & 63;
  const int wave = tid >> 6;
  const int wm = wave & 1, wn = wave >> 1;
  const int fr = lane & 15;            // frag row (m for A, n for B)
  const int fq = (lane >> 4) * 8;      // frag k offset

  const unsigned short* Bsrc = WibT + (size_t)g * NH * NI;

  floatx4 acc[4][4];
#pragma unroll
  for (int a = 0; a < 4; a++)
#pragma unroll
    for (int b = 0; b < 4; b++)
#pragma unroll
      for (int z = 0; z < 4; z++) acc[a][b][z] = 0.0f;

  for (int k0 = 0; k0 < NI; k0 += 32) {
#pragma unroll
    for (int it = 0; it < 2; it++) {
      int c = tid + it * 256;            // 0..511
      int row = c >> 2, kc = (c & 3) * 8;
      *(uint4*)(&As[row][kc]) = *(const uint4*)(Xb + (size_t)(m0 + row) * NI + k0 + kc);
      *(uint4*)(&Bs[row][kc]) = *(const uint4*)(Bsrc + (size_t)(n0 + row) * NI + k0 + kc);
    }
    __syncthreads();
    short8 af[4], bf[4];
#pragma unroll
    for (int ms = 0; ms < 4; ms++) af[ms] = *(const short8*)(&As[wm * 64 + ms * 16 + fr][fq]);
#pragma unroll
    for (int ns = 0; ns < 4; ns++) bf[ns] = *(const short8*)(&Bs[wn * 64 + ns * 16 + fr][fq]);
#pragma unroll
    for (int ms = 0; ms < 4; ms++)
#pragma unroll
      for (int ns = 0; ns < 4; ns++)
        acc[ms][ns] = __builtin_amdgcn_mfma_f32_16x16x32_bf16(af[ms], bf[ns], acc[ms][ns], 0, 0, 0);
    __syncthreads();
  }

  // Epilogue: bias add + bf16 + scatter into LDS stage in Zq order, then
  // coalesced copy out (two contiguous 16 KB spans, one per t' in this tile).
#pragma unroll
  for (int ns = 0; ns < 4; ns++) {
    int jrel = wn * 64 + ns * 16 + fr;        // col - n0, 0..127
    float bs = bias[g * NH + n0 + jrel];
    int bkp = jrel >> 3, jj = jrel & 7;
#pragma unroll
    for (int ms = 0; ms < 4; ms++) {
#pragma unroll
      for (int r = 0; r < 4; r++) {
        int mrel = wm * 64 + ms * 16 + (lane >> 4) * 4 + r;   // 0..127
        int tp = mrel >> 6, b = mrel & 63;
        int wm2 = b >> 5, row32 = b & 31;
        int half2 = (row32 >> 2) & 1;
        int rr = (row32 & 3) | ((row32 >> 3) << 2);
        int idx = (((((tp * 16 + bkp) * 2 + wm2) * 2 + half2) * 8 + jj) * 16) + rr;
        stg[idx] = f2bf(acc[ms][ns][r] + bs);
      }
    }
  }
  __syncthreads();
  const size_t t0 = (size_t)(m0 >> 6);
  const int bk0 = n0 >> 3;
#pragma unroll
  for (int tp = 0; tp < 2; tp++) {
    size_t gbase = (((t0 + tp) * 4 + g) * 128 + bk0) * 512;   // elements
#pragma unroll
    for (int c = 0; c < 4; c++) {
      int e = c * 2048 + tid * 8;
      *(uint4*)(Zq + gbase + e) = *(const uint4*)(stg + tp * 8192 + e);
    }
  }
}

// ---------------- persistent recurrent kernel ----------------
// R6 changes vs R5 (11.1 us/step):
//  * REGRESSION FIX: Zq prefetch issued AFTER the flag post (R5 issued it before the
//    release vmcnt(0), putting 2 nt HBM loads on the flag-post path: ~+0.7 us/step).
//  * A-window depth 16 -> 32 (32 KB in flight/wave): h-broadcast served in 2
//    latency-rounds instead of 4.
//  * Per-block chunk rotation S = (bk&3)*16 (4 compile-time instantiations):
//    de-correlates the post-barrier thundering herd -- previously all 128 blocks
//    requested the SAME h lines in the SAME order; now 4 phase groups spread the
//    same-line demand across the 64-chunk sequence.
//  Sync protocol identical to R4/R5 (verified): WT h stores + vmcnt(0) + packed
//  flags + bypass loads; WAW-safe via the full barrier + double buffer.

template<int C>
__device__ __forceinline__ void load_a_c(const unsigned short* ap, short8 (&areg)[64]) {
  asm volatile("global_load_dwordx4 %0, %1, off offset:%2 sc0 sc1"
               : "=v"(areg[C]) : "v"(ap), "i"(C * 32));
}

template<int C>
__device__ __forceinline__ void load_b_c(const unsigned short* bfr, int lane, short8 (&bs)[64]) {
  bs[C] = *(const short8*)(&bfr[((size_t)(C * 64) + lane) * 8]);
}

template<int S, int I>
struct PrologR {
  static __device__ __forceinline__ void run(const unsigned short* ap, short8 (&areg)[64]) {
    load_a_c<(S + I) & 63>(ap, areg);
    PrologR<S, I + 1>::run(ap, areg);
  }
};
template<int S>
struct PrologR<S, DEPTH> {
  static __device__ __forceinline__ void run(const unsigned short*, short8 (&)[64]) {}
};

template<int S, int I>
struct ChunksR {
  static __device__ __forceinline__ void run(const unsigned short* ap, const unsigned short* bfr,
                                             int lane, short8 (&areg)[64], short8 (&bs)[64],
                                             floatx16& acc0, floatx16& acc1) {
    if constexpr (I + DEPTH < 64) load_a_c<(S + I + DEPTH) & 63>(ap, areg);
    if constexpr (I + 4 < 64) load_b_c<(S + I + 4) & 63>(bfr, lane, bs);
    constexpr int NOUT = (I + DEPTH < 64) ? DEPTH : (63 - I);
    constexpr int C = (S + I) & 63;
    // wait chunk C; "+v" tie makes the MFMA data-dependent on this asm (rule #18),
    // "memory" pins later vmem below the counted region.
    asm volatile("s_waitcnt vmcnt(%1)" : "+v"(areg[C]) : "i"(NOUT) : "memory");
    if constexpr ((I & 1) == 0)
      acc0 = __builtin_amdgcn_mfma_f32_32x32x16_bf16(areg[C], bs[C], acc0, 0, 0, 0);
    else
      acc1 = __builtin_amdgcn_mfma_f32_32x32x16_bf16(areg[C], bs[C], acc1, 0, 0, 0);
    ChunksR<S, I + 1>::run(ap, bfr, lane, areg, bs, acc0, acc1);
  }
};
template<int S>
struct ChunksR<S, 64> {
  static __device__ __forceinline__ void run(const unsigned short*, const unsigned short*,
                                             int, short8 (&)[64], short8 (&)[64],
                                             floatx16&, floatx16&) {}
};

template<int S>
__device__ __forceinline__ void lstm_step(
    int t, const unsigned short* __restrict__ Zq, unsigned short* __restrict__ hbuf,
    unsigned* __restrict__ flags, float* __restrict__ out,
    const unsigned short* bfr, const unsigned long long* fpq,
    int tid, int lane, int wm, int nl, int g0, int jj, int half, int bk, int j0,
    size_t zoff, const int (&brow)[16], float (&creg)[16],
    uint4 (&zc)[2], uint4 (&zn)[2]) {
  const int hsz = NB * NH;

  // ---- arrive: all 128 flags >= t (packed; dwordx2 per lane, agent-scope) ----
  if (t) {
    unsigned tgt = (unsigned)t;
    for (;;) {
      unsigned long long fv = __hip_atomic_load(fpq, __ATOMIC_RELAXED,
                                                __HIP_MEMORY_SCOPE_AGENT);
      unsigned a = (unsigned)fv, b2 = (unsigned)(fv >> 32);
      if (__all((int)((a >= tgt) && (b2 >= tgt)))) break;
      __builtin_amdgcn_s_sleep(1);
    }
  }
  // clean vmcnt domain before the counted A-load window (drains out/Zq leftovers)
  asm volatile("s_waitcnt vmcnt(0)" ::: "memory");
  __builtin_amdgcn_sched_barrier(0);

  const unsigned short* hin = hbuf + (size_t)(t & 1) * hsz;
  unsigned short* hout = hbuf + (size_t)((t + 1) & 1) * hsz;
  const unsigned short* ap = hin + (size_t)(wm * 32 + nl) * NH + half * 8;

  floatx16 acc0, acc1;
#pragma unroll
  for (int z = 0; z < 16; z++) { acc0[z] = 0.0f; acc1[z] = 0.0f; }

  short8 areg[64];
  short8 bs[64];
  PrologR<S, 0>::run(ap, areg);      // issue A chunks S..S+31 (bypass loads)
  load_b_c<(S + 0) & 63>(bfr, lane, bs);
  load_b_c<(S + 1) & 63>(bfr, lane, bs);
  load_b_c<(S + 2) & 63>(bfr, lane, bs);
  load_b_c<(S + 3) & 63>(bfr, lane, bs);
  ChunksR<S, 0>::run(ap, bfr, lane, areg, bs, acc0, acc1);
  __builtin_amdgcn_sched_barrier(0);

#pragma unroll
  for (int z = 0; z < 16; z++) acc0[z] += acc1[z];

  // unpack this step's Zq chunk (regs valid: drained by window's final vmcnt(0))
  unsigned zd[8];
  zd[0] = zc[0].x; zd[1] = zc[0].y; zd[2] = zc[0].z; zd[3] = zc[0].w;
  zd[4] = zc[1].x; zd[5] = zc[1].y; zd[6] = zc[1].z; zd[7] = zc[1].w;

  float harr[16];
  // epilogue: gather all 4 gates across the quad {l, l^8, l^16, l^24}
#pragma unroll
  for (int r = 0; r < 16; r++) {
    unsigned dw = zd[r >> 1];
    float zxv = bf2f((unsigned short)((r & 1) ? (dw >> 16) : (dw & 0xffffu)));
    float z0 = acc0[r] + zxv;            // gate g0
    float z1 = __shfl_xor(z0, 8);        // gate g0^1
    float z2 = __shfl_xor(z0, 16);       // gate g0^2
    float z3 = __shfl_xor(z1, 16);       // gate g0^3
    bool bb0 = (g0 & 1) != 0, bb1 = (g0 & 2) != 0;
    float zf = bb1 ? (bb0 ? z3 : z2) : (bb0 ? z1 : z0);  // zq[g0]
    float zi = bb1 ? (bb0 ? z2 : z3) : (bb0 ? z0 : z1);  // zq[1^g0]
    float zg = bb1 ? (bb0 ? z1 : z0) : (bb0 ? z3 : z2);  // zq[2^g0]
    float zo = bb1 ? (bb0 ? z0 : z1) : (bb0 ? z2 : z3);  // zq[3^g0]
    float fg = sigmoid_f(zf);
    float ig = sigmoid_f(zi);
    float gg = tanh_f(zg);
    float og = sigmoid_f(zo);
    float c = fg * creg[r] + ig * gg;
    creg[r] = c;
    float h = og * tanh_f(c);
    harr[r] = h;
    if (g0 == 0) {  // one writer per (b, j) quad; agent-scope WT -> LLC
      __hip_atomic_store(&hout[(size_t)brow[r] * NH + j0 + jj], f2bf(h),
                         __ATOMIC_RELAXED, __HIP_MEMORY_SCOPE_AGENT);
    }
  }

  if (t + 1 < T_STEPS) {
    // ---- release: h stores at coherence point, then post flag ----
    asm volatile("s_waitcnt vmcnt(0)" ::: "memory");
    __syncthreads();                                   // both waves drained
    if (tid == 0)
      __hip_atomic_store(flags + bk, (unsigned)(t + 1),
                         __ATOMIC_RELAXED, __HIP_MEMORY_SCOPE_AGENT);
    // Zq prefetch for t+1: OFF the release path; drains in next spin / window wait.
    const unsigned short* zp = Zq + (size_t)(t + 1) * 262144 + zoff;
    asm volatile("global_load_dwordx4 %0, %1, off nt" : "=v"(zn[0]) : "v"(zp));
    asm volatile("global_load_dwordx4 %0, %1, off offset:16 nt" : "=v"(zn[1]) : "v"(zp));
  }

  // out stores off the release path (nt: bypass caches, drain during next spin)
  if (g0 == 0) {
#pragma unroll
    for (int r = 0; r < 16; r++) {
      size_t oidx = (size_t)brow[r] * NH + j0 + jj;
      __builtin_nontemporal_store(harr[r], &out[(size_t)t * hsz + oidx]);
      if (t == T_STEPS - 1)
        __builtin_nontemporal_store(harr[r], &out[(size_t)T_STEPS * hsz + oidx]);  // h_n
    }
  }
}

template<int S>
__device__ __forceinline__ void lstm_loop(
    const unsigned short* __restrict__ Zq, unsigned short* __restrict__ hbuf,
    unsigned* __restrict__ flags, float* __restrict__ out,
    const unsigned short* bfr, const unsigned long long* fpq,
    int tid, int lane, int wm, int nl, int g0, int jj, int half, int bk, int j0,
    size_t zoff, const int (&brow)[16], float (&creg)[16]) {
  uint4 zA[2], zB[2];
  {  // t=0 prefetch (drained by the t=0 step-top vmcnt(0) + window wait)
    const unsigned short* zp = Zq + zoff;
    asm volatile("global_load_dwordx4 %0, %1, off nt" : "=v"(zA[0]) : "v"(zp));
    asm volatile("global_load_dwordx4 %0, %1, off offset:16 nt" : "=v"(zA[1]) : "v"(zp));
  }
  for (int t2 = 0; t2 < T_STEPS; t2 += 2) {
    lstm_step<S>(t2,     Zq, hbuf, flags, out, bfr, fpq, tid, lane, wm, nl, g0, jj,
                 half, bk, j0, zoff, brow, creg, zA, zB);
    lstm_step<S>(t2 + 1, Zq, hbuf, flags, out, bfr, fpq, tid, lane, wm, nl, g0, jj,
                 half, bk, j0, zoff, brow, creg, zB, zA);
  }
}

__global__ __launch_bounds__(128, 1) void lstm_persist(
    const unsigned short* __restrict__ Zq,
    const unsigned short* __restrict__ WhT,   // [4][NH(n)][NH(k)] bf16
    const float* __restrict__ c0,
    unsigned short* __restrict__ hbuf,        // 2 x NB x NH bf16
    unsigned* __restrict__ flags,             // NBLK packed dwords
    float* __restrict__ out) {
  __shared__ __align__(16) unsigned short bfr[64 * 64 * 8];  // [kk][lane][8] = 64 KB

  const int bk = blockIdx.x;
  const int j0 = bk * 8;
  const int tid = threadIdx.x;
  const int lane = tid & 63;
  const int wm = tid >> 6;        // wave = batch half (m-tile of 32)
  const int nl = lane & 31;       // MFMA col n (0..31): gate g0 = n>>3, h-col jj = n&7
  const int g0 = nl >> 3;
  const int jj = nl & 7;
  const int half = lane >> 5;

  // Fill B fragments: B[k][n] = Wh[g][k][j0+jj] = WhT[g][j0+jj][k]
  for (int i = 0; i < 32; i++) {
    int f = tid + i * 128;        // 0..4095 = kk*64 + lane
    int fl = f & 63, kk = f >> 6;
    int n = fl & 31;
    size_t wrow = (size_t)((n >> 3) * NH + j0 + (n & 7));
    int kb = kk * 16 + (fl >> 5) * 8;
    uint4 v = *(const uint4*)(WhT + wrow * NH + kb);
    *(uint4*)(&bfr[(size_t)f * 8]) = v;
  }

  // c state in C/D layout: row = (r&3) + 8*(r>>2) + 4*half  (rows within 32-tile)
  float creg[16];
  int brow[16];
#pragma unroll
  for (int r = 0; r < 16; r++) {
    brow[r] = wm * 32 + (r & 3) + 8 * (r >> 2) + 4 * half;
    creg[r] = c0[(size_t)brow[r] * NH + j0 + jj];
  }
  __syncthreads();

  const unsigned long long* fpq = (const unsigned long long*)flags + lane;
  const size_t zoff = (((((size_t)g0 * 128 + bk) * 2 + wm) * 2 + half) * 8 + jj) * 16;

  switch (bk & 3) {
    case 0: lstm_loop<0>(Zq, hbuf, flags, out, bfr, fpq, tid, lane, wm, nl, g0, jj,
                         half, bk, j0, zoff, brow, creg); break;
    case 1: lstm_loop<16>(Zq, hbuf, flags, out, bfr, fpq, tid, lane, wm, nl, g0, jj,
                          half, bk, j0, zoff, brow, creg); break;
    case 2: lstm_loop<32>(Zq, hbuf, flags, out, bfr, fpq, tid, lane, wm, nl, g0, jj,
                          half, bk, j0, zoff, brow, creg); break;
    default: lstm_loop<48>(Zq, hbuf, flags, out, bfr, fpq, tid, lane, wm, nl, g0, jj,
                           half, bk, j0, zoff, brow, creg); break;
  }

  // c_n
  if (g0 == 0) {
#pragma unroll
    for (int r = 0; r < 16; r++)
      __builtin_nontemporal_store(
          creg[r], &out[(size_t)T_STEPS * NB * NH + NB * NH + (size_t)brow[r] * NH + j0 + jj]);
  }
}

// ---------------- host launcher ----------------
extern "C" void kernel_launch(void* const* d_in, const int* in_sizes, int n_in,
                              void* d_out, int out_size, void* d_ws, size_t ws_size,
                              hipStream_t stream) {
  const float* X  = (const float*)d_in[0];
  const float* h0 = (const float*)d_in[1];
  const float* c0 = (const float*)d_in[2];
  const float* Wi = (const float*)d_in[3];
  const float* Wh = (const float*)d_in[4];
  const float* bi = (const float*)d_in[5];
  const float* bh = (const float*)d_in[6];
  float* out = (float*)d_out;

  uint8_t* ws = (uint8_t*)d_ws;
  size_t off = 0;
  auto alloc = [&](size_t bytes) -> void* {
    void* p = ws + off;
    off += (bytes + 255) & ~(size_t)255;
    return p;
  };
  unsigned short* Zq   = (unsigned short*)alloc((size_t)T_STEPS * NB * 4096 * 2);  // 268 MB
  unsigned short* Xb   = (unsigned short*)alloc((size_t)T_STEPS * NB * NI * 2);    // 33.6 MB
  unsigned short* WibT = (unsigned short*)alloc((size_t)4 * NH * NI * 2);          // 4.2 MB
  unsigned short* WhT  = (unsigned short*)alloc((size_t)4 * NH * NH * 2);          // 8.4 MB
  float* bias          = (float*)alloc((size_t)4 * NH * 4);
  unsigned short* hbuf = (unsigned short*)alloc((size_t)2 * NB * NH * 2);
  unsigned* flags      = (unsigned*)alloc((size_t)NBLK * 32 * 4);                  // 16 KB (packed: first 512 B used)

  if (off > ws_size) {
    hipMemsetAsync(d_out, 0x7F, (size_t)out_size * 4, stream);
    return;
  }

  convert_x<<<16384, 256, 0, stream>>>(X, Xb);
  transpose_bf16<<<dim3(8, 16, 4), 256, 0, stream>>>(Wi, WibT, NI, NH);
  transpose_bf16<<<dim3(16, 16, 4), 256, 0, stream>>>(Wh, WhT, NH, NH);
  prep_small<<<256, 256, 0, stream>>>(bi, bh, h0, bias, hbuf, flags);
  gemm_zx<<<dim3(256, 8, 4), 256, 0, stream>>>(Xb, WibT, bias, Zq);

  lstm_persist<<<dim3(NBLK), dim3(128), 0, stream>>>(Zq, WhT, c0, hbuf, flags, out);
}